// Round 1
// baseline (452.819 us; speedup 1.0000x reference)
//
#include <hip/hip_runtime.h>

#define N_NODES 50000
#define N_EDGES 800000
#define DIM 128

// ---------------- CSR build ----------------

__global__ __launch_bounds__(256) void k_count(const int* __restrict__ dst, int* __restrict__ deg) {
    int e = blockIdx.x * 256 + threadIdx.x;
    if (e < N_EDGES) atomicAdd(&deg[dst[e]], 1);
}

__global__ __launch_bounds__(1024) void k_scan(const int* __restrict__ deg, int* __restrict__ rowptr) {
    __shared__ int sm[1024];
    int t = threadIdx.x;
    const int chunk = (N_NODES + 1023) >> 10;   // 49
    int beg = t * chunk;
    int end = beg + chunk;
    if (beg > N_NODES) beg = N_NODES;
    if (end > N_NODES) end = N_NODES;
    int sum = 0;
    for (int i = beg; i < end; ++i) sum += deg[i];
    sm[t] = sum;
    __syncthreads();
    // inclusive Hillis-Steele scan over 1024 partials
    for (int off = 1; off < 1024; off <<= 1) {
        int v = (t >= off) ? sm[t - off] : 0;
        __syncthreads();
        sm[t] += v;
        __syncthreads();
    }
    int run = sm[t] - sum;   // exclusive prefix for this thread's chunk
    for (int i = beg; i < end; ++i) { rowptr[i] = run; run += deg[i]; }
    if (t == 0) rowptr[N_NODES] = N_EDGES;
}

__global__ __launch_bounds__(256) void k_scatter(const int* __restrict__ src, const int* __restrict__ dst,
                                                 const int* __restrict__ rowptr, int* __restrict__ fill,
                                                 int* __restrict__ srt) {
    int e = blockIdx.x * 256 + threadIdx.x;
    if (e < N_EDGES) {
        int d = dst[e];
        int p = atomicAdd(&fill[d], 1);
        srt[rowptr[d] + p] = src[e];
    }
}

// ---------------- mean aggregation: one wave per node ----------------

__global__ __launch_bounds__(256) void k_aggregate(const float* __restrict__ X, const int* __restrict__ rowptr,
                                                   const int* __restrict__ srt, float* __restrict__ out) {
    int w = (blockIdx.x * 256 + threadIdx.x) >> 6;   // node id
    int lane = threadIdx.x & 63;                     // owns cols 2*lane, 2*lane+1
    if (w >= N_NODES) return;
    int beg = rowptr[w], end = rowptr[w + 1];
    float ax = 0.f, ay = 0.f;
    for (int e = beg; e < end; ++e) {
        int s = srt[e];
        float2 v = *(const float2*)(X + (size_t)s * DIM + lane * 2);
        ax += v.x; ay += v.y;
    }
    float inv = 1.0f / fmaxf((float)(end - beg), 1.0f);
    float2 r; r.x = ax * inv; r.y = ay * inv;
    *(float2*)(out + (size_t)w * DIM + lane * 2) = r;
}

// ---------------- fused dual GEMM: C = relu(A1 @ Wl^T + A2 @ Wr^T + b) ----------------
// A1,A2: [M,128] row-major.  Wl,Wr: [128(n),128(k)] row-major.  C: [M,128].
// Tile: 64 rows x 128 cols per block of 256 threads; K-loop over concat K=256.

__global__ __launch_bounds__(256) void k_gemm(const float* __restrict__ A1, const float* __restrict__ A2,
                                              const float* __restrict__ Wl, const float* __restrict__ Wr,
                                              const float* __restrict__ bias, float* __restrict__ C) {
    __shared__ float As[64][36];    // 64 rows x 32 k, stride 36 (16B-aligned rows)
    __shared__ float Ws[32][132];   // 32 k x 128 n, stride 132 (16B-aligned rows)
    int t = threadIdx.x;
    int row0 = blockIdx.x * 64;
    int tn = t & 15;    // owns cols tn*8 .. tn*8+7
    int tm = t >> 4;    // owns rows tm*4 .. tm*4+3
    float acc[4][8];
#pragma unroll
    for (int i = 0; i < 4; ++i)
#pragma unroll
        for (int j = 0; j < 8; ++j) acc[i][j] = 0.f;

    for (int ks = 0; ks < 256; ks += 32) {
        const float* Asrc = (ks < 128) ? A1 : A2;
        const float* Wsrc = (ks < 128) ? Wl : Wr;
        int kof = ks & 127;
        // stage A tile 64x32 (each thread: 2x float4)
        {
            int r = t >> 3;            // 0..31
            int c4 = (t & 7) * 4;      // 0..28
#pragma unroll
            for (int rr = 0; rr < 64; rr += 32) {
                int row = row0 + r + rr;
                float4 v = make_float4(0.f, 0.f, 0.f, 0.f);
                if (row < N_NODES) v = *(const float4*)(Asrc + (size_t)row * DIM + kof + c4);
                *(float4*)&As[r + rr][c4] = v;
            }
        }
        // stage W tile 32(k) x 128(n), transposed on the fly
        {
            int nrow = t >> 3;         // 0..31
            int c4 = (t & 7) * 4;      // k offset within 32
#pragma unroll
            for (int nn = 0; nn < 128; nn += 32) {
                float4 v = *(const float4*)(Wsrc + (size_t)(nrow + nn) * DIM + kof + c4);
                Ws[c4 + 0][nrow + nn] = v.x;
                Ws[c4 + 1][nrow + nn] = v.y;
                Ws[c4 + 2][nrow + nn] = v.z;
                Ws[c4 + 3][nrow + nn] = v.w;
            }
        }
        __syncthreads();
#pragma unroll
        for (int kk = 0; kk < 32; ++kk) {
            float a0 = As[tm * 4 + 0][kk];
            float a1 = As[tm * 4 + 1][kk];
            float a2 = As[tm * 4 + 2][kk];
            float a3 = As[tm * 4 + 3][kk];
            float4 w0 = *(float4*)&Ws[kk][tn * 8];
            float4 w1 = *(float4*)&Ws[kk][tn * 8 + 4];
            float wv[8] = {w0.x, w0.y, w0.z, w0.w, w1.x, w1.y, w1.z, w1.w};
#pragma unroll
            for (int j = 0; j < 8; ++j) {
                acc[0][j] += a0 * wv[j];
                acc[1][j] += a1 * wv[j];
                acc[2][j] += a2 * wv[j];
                acc[3][j] += a3 * wv[j];
            }
        }
        __syncthreads();
    }
    float bv[8];
#pragma unroll
    for (int j = 0; j < 8; ++j) bv[j] = bias[tn * 8 + j];
#pragma unroll
    for (int i = 0; i < 4; ++i) {
        int row = row0 + tm * 4 + i;
        if (row < N_NODES) {
            float4 o0, o1;
            o0.x = fmaxf(acc[i][0] + bv[0], 0.f);
            o0.y = fmaxf(acc[i][1] + bv[1], 0.f);
            o0.z = fmaxf(acc[i][2] + bv[2], 0.f);
            o0.w = fmaxf(acc[i][3] + bv[3], 0.f);
            o1.x = fmaxf(acc[i][4] + bv[4], 0.f);
            o1.y = fmaxf(acc[i][5] + bv[5], 0.f);
            o1.z = fmaxf(acc[i][6] + bv[6], 0.f);
            o1.w = fmaxf(acc[i][7] + bv[7], 0.f);
            *(float4*)(C + (size_t)row * DIM + tn * 8) = o0;
            *(float4*)(C + (size_t)row * DIM + tn * 8 + 4) = o1;
        }
    }
}

// ---------------- launch ----------------

extern "C" void kernel_launch(void* const* d_in, const int* in_sizes, int n_in,
                              void* d_out, int out_size, void* d_ws, size_t ws_size,
                              hipStream_t stream) {
    const float* x   = (const float*)d_in[0];
    const int*   ei  = (const int*)d_in[1];
    const float* W1l = (const float*)d_in[2];
    const float* b1  = (const float*)d_in[3];
    const float* W1r = (const float*)d_in[4];
    const float* W2l = (const float*)d_in[5];
    const float* b2  = (const float*)d_in[6];
    const float* W2r = (const float*)d_in[7];
    float* out = (float*)d_out;

    const int* src = ei;             // edge_index[0]
    const int* dst = ei + N_EDGES;   // edge_index[1]

    char* ws = (char*)d_ws;
    int*   deg    = (int*)(ws + 0);         // 200000 B
    int*   fill   = (int*)(ws + 200064);    // 200000 B
    int*   rowptr = (int*)(ws + 400128);    // 200004 B
    int*   srt    = (int*)(ws + 600192);    // 3.2 MB
    float* agg    = (float*)(ws + 3800320); // 25.6 MB  (total ~29.4 MB)

    // zero deg + fill each call (covers both regions)
    hipMemsetAsync(ws, 0, 400128, stream);

    dim3 blkE(256), grdE((N_EDGES + 255) / 256);
    k_count<<<grdE, blkE, 0, stream>>>(dst, deg);
    k_scan<<<1, 1024, 0, stream>>>(deg, rowptr);
    k_scatter<<<grdE, blkE, 0, stream>>>(src, dst, rowptr, fill, srt);

    dim3 grdA((N_NODES * 64 + 255) / 256);   // one wave per node
    dim3 grdG((N_NODES + 63) / 64);

    // layer 1: h (-> d_out) = relu(agg1 @ W1l^T + b1 + x @ W1r^T)
    k_aggregate<<<grdA, blkE, 0, stream>>>(x, rowptr, srt, agg);
    k_gemm<<<grdG, blkE, 0, stream>>>(agg, x, W1l, W1r, b1, out);

    // layer 2: out = relu(agg2 @ W2l^T + b2 + h @ W2r^T), in-place over h
    k_aggregate<<<grdA, blkE, 0, stream>>>(out, rowptr, srt, agg);
    k_gemm<<<grdG, blkE, 0, stream>>>(agg, out, W2l, W2r, b2, out);
}

// Round 2
// 371.626 us; speedup vs baseline: 1.2185x; 1.2185x over previous
//
#include <hip/hip_runtime.h>

#define N_NODES 50000
#define N_EDGES 800000
#define DIM 128

typedef __bf16 bf16;
typedef __bf16 bf16x2 __attribute__((ext_vector_type(2)));
typedef __bf16 bf16x4 __attribute__((ext_vector_type(4)));
typedef __bf16 bf16x8 __attribute__((ext_vector_type(8)));
typedef float  f32x4  __attribute__((ext_vector_type(4)));

// ---------------- CSR build ----------------

__global__ __launch_bounds__(256) void k_count(const int* __restrict__ dst, int* __restrict__ deg) {
    int e = blockIdx.x * 256 + threadIdx.x;
    if (e < N_EDGES) atomicAdd(&deg[dst[e]], 1);
}

__global__ __launch_bounds__(1024) void k_scan(const int* __restrict__ deg, int* __restrict__ rowptr) {
    __shared__ int sm[1024];
    int t = threadIdx.x;
    const int chunk = (N_NODES + 1023) >> 10;
    int beg = t * chunk;
    int end = beg + chunk;
    if (beg > N_NODES) beg = N_NODES;
    if (end > N_NODES) end = N_NODES;
    int sum = 0;
    for (int i = beg; i < end; ++i) sum += deg[i];
    sm[t] = sum;
    __syncthreads();
    for (int off = 1; off < 1024; off <<= 1) {
        int v = (t >= off) ? sm[t - off] : 0;
        __syncthreads();
        sm[t] += v;
        __syncthreads();
    }
    int run = sm[t] - sum;
    for (int i = beg; i < end; ++i) { rowptr[i] = run; run += deg[i]; }
    if (t == 0) rowptr[N_NODES] = N_EDGES;
}

__global__ __launch_bounds__(256) void k_scatter(const int* __restrict__ src, const int* __restrict__ dst,
                                                 const int* __restrict__ rowptr, int* __restrict__ fill,
                                                 int* __restrict__ srt) {
    int e = blockIdx.x * 256 + threadIdx.x;
    if (e < N_EDGES) {
        int d = dst[e];
        int p = atomicAdd(&fill[d], 1);
        srt[rowptr[d] + p] = src[e];
    }
}

// ---------------- f32 -> bf16 convert ----------------

__global__ __launch_bounds__(256) void k_xtobf(const float* __restrict__ x, bf16* __restrict__ xb) {
    int i = blockIdx.x * 256 + threadIdx.x;   // one float4 per thread
    if (i < (N_NODES * DIM) / 4) {
        float4 v = *(const float4*)(x + (size_t)i * 4);
        bf16x4 o;
        o[0] = (bf16)v.x; o[1] = (bf16)v.y; o[2] = (bf16)v.z; o[3] = (bf16)v.w;
        *(bf16x4*)(xb + (size_t)i * 4) = o;
    }
}

// ---------------- weight split: Wcat[n][k] (k<128: W_l, k>=128: W_r) -> hi/lo bf16 ----------------

__global__ __launch_bounds__(256) void k_splitW(const float* __restrict__ W1l, const float* __restrict__ W1r,
                                                const float* __restrict__ W2l, const float* __restrict__ W2r,
                                                bf16* __restrict__ Wh1, bf16* __restrict__ Wl1,
                                                bf16* __restrict__ Wh2, bf16* __restrict__ Wl2) {
    int t = blockIdx.x * 256 + threadIdx.x;   // 65536 threads: 2 layers x 32768 elems
    if (t >= 65536) return;
    int layer = t >> 15;
    int idx = t & 32767;
    int n = idx >> 8;
    int k = idx & 255;
    const float* Wl_ = layer ? W2l : W1l;
    const float* Wr_ = layer ? W2r : W1r;
    float w = (k < 128) ? Wl_[n * 128 + k] : Wr_[n * 128 + (k - 128)];
    bf16 hi = (bf16)w;
    bf16 lo = (bf16)(w - (float)hi);
    bf16* Wh = layer ? Wh2 : Wh1;
    bf16* Wlo = layer ? Wl2 : Wl1;
    Wh[idx] = hi;
    Wlo[idx] = lo;
}

// ---------------- mean aggregation: one wave per node, bf16 gather ----------------

__global__ __launch_bounds__(256) void k_aggregate(const bf16* __restrict__ X, const int* __restrict__ rowptr,
                                                   const int* __restrict__ srt, bf16* __restrict__ out) {
    int w = (blockIdx.x * 256 + threadIdx.x) >> 6;   // node id
    int lane = threadIdx.x & 63;                     // owns cols 2*lane, 2*lane+1
    if (w >= N_NODES) return;
    int beg = rowptr[w], end = rowptr[w + 1];
    float ax = 0.f, ay = 0.f;
    for (int e = beg; e < end; ++e) {
        int s = srt[e];
        bf16x2 v = *(const bf16x2*)(X + (size_t)s * DIM + lane * 2);
        ax += (float)v[0]; ay += (float)v[1];
    }
    float inv = 1.0f / fmaxf((float)(end - beg), 1.0f);
    bf16x2 r;
    r[0] = (bf16)(ax * inv);
    r[1] = (bf16)(ay * inv);
    *(bf16x2*)(out + (size_t)w * DIM + lane * 2) = r;
}

// ---------------- MFMA dual GEMM: C = relu([agg|self] @ [Wl|Wr]^T + b) ----------------
// A1b: [M][128] bf16 (agg).  A2: [M][128] f32 (self, hi/lo split on the fly).
// Wh/Wl: [128 n][256 k] bf16 presplit.  C: [M][128] f32.  Cb: optional bf16 copy.
// Block: 256 thr = 4 waves, tile 64(M) x 128(N); each wave 16 rows x 128 cols.

__global__ __launch_bounds__(256) void k_gemm(const bf16* __restrict__ A1b, const float* __restrict__ A2,
                                              const bf16* __restrict__ Wh, const bf16* __restrict__ Wl,
                                              const float* __restrict__ bias, float* __restrict__ C,
                                              bf16* __restrict__ Cb) {
    __shared__ bf16 Ah[64][36];
    __shared__ bf16 Al[64][36];
    __shared__ bf16 Bh[128][36];
    __shared__ bf16 Bl[128][36];
    int t = threadIdx.x;
    int row0 = blockIdx.x * 64;
    int wave = t >> 6, lane = t & 63;
    int r = lane & 15, g = lane >> 4;

    f32x4 acc[8];
#pragma unroll
    for (int i = 0; i < 8; ++i) acc[i] = (f32x4){0.f, 0.f, 0.f, 0.f};

    for (int ks = 0; ks < 256; ks += 32) {
        bool split = (ks >= 128);
        int kof = ks & 127;
        // ---- stage A tile 64x32 ----
        {
            int ar = t >> 2;          // 0..63
            int ac = (t & 3) * 8;     // 0,8,16,24
            int grow = row0 + ar;
            if (!split) {
                bf16x8 v;
#pragma unroll
                for (int j = 0; j < 8; ++j) v[j] = (bf16)0.f;
                if (grow < N_NODES) v = *(const bf16x8*)(A1b + (size_t)grow * DIM + kof + ac);
                bf16x4 v0 = __builtin_shufflevector(v, v, 0, 1, 2, 3);
                bf16x4 v1 = __builtin_shufflevector(v, v, 4, 5, 6, 7);
                *(bf16x4*)&Ah[ar][ac] = v0;
                *(bf16x4*)&Ah[ar][ac + 4] = v1;
            } else {
                float f[8] = {0.f, 0.f, 0.f, 0.f, 0.f, 0.f, 0.f, 0.f};
                if (grow < N_NODES) {
                    float4 v0 = *(const float4*)(A2 + (size_t)grow * DIM + kof + ac);
                    float4 v1 = *(const float4*)(A2 + (size_t)grow * DIM + kof + ac + 4);
                    f[0] = v0.x; f[1] = v0.y; f[2] = v0.z; f[3] = v0.w;
                    f[4] = v1.x; f[5] = v1.y; f[6] = v1.z; f[7] = v1.w;
                }
                bf16x4 h0, h1, l0, l1;
#pragma unroll
                for (int j = 0; j < 4; ++j) {
                    bf16 h = (bf16)f[j];
                    h0[j] = h; l0[j] = (bf16)(f[j] - (float)h);
                }
#pragma unroll
                for (int j = 0; j < 4; ++j) {
                    bf16 h = (bf16)f[4 + j];
                    h1[j] = h; l1[j] = (bf16)(f[4 + j] - (float)h);
                }
                *(bf16x4*)&Ah[ar][ac] = h0;
                *(bf16x4*)&Ah[ar][ac + 4] = h1;
                *(bf16x4*)&Al[ar][ac] = l0;
                *(bf16x4*)&Al[ar][ac + 4] = l1;
            }
        }
        // ---- stage W tile 128x32 (bf16 presplit, direct copy) ----
        {
            int br = t >> 1;          // 0..127
            int bc = (t & 1) * 16;    // 0,16
            const bf16* sh = Wh + (size_t)br * 256 + ks + bc;
            const bf16* sl = Wl + (size_t)br * 256 + ks + bc;
            bf16x8 h0 = *(const bf16x8*)sh;
            bf16x8 h1 = *(const bf16x8*)(sh + 8);
            bf16x8 l0 = *(const bf16x8*)sl;
            bf16x8 l1 = *(const bf16x8*)(sl + 8);
            *(bf16x4*)&Bh[br][bc]      = __builtin_shufflevector(h0, h0, 0, 1, 2, 3);
            *(bf16x4*)&Bh[br][bc + 4]  = __builtin_shufflevector(h0, h0, 4, 5, 6, 7);
            *(bf16x4*)&Bh[br][bc + 8]  = __builtin_shufflevector(h1, h1, 0, 1, 2, 3);
            *(bf16x4*)&Bh[br][bc + 12] = __builtin_shufflevector(h1, h1, 4, 5, 6, 7);
            *(bf16x4*)&Bl[br][bc]      = __builtin_shufflevector(l0, l0, 0, 1, 2, 3);
            *(bf16x4*)&Bl[br][bc + 4]  = __builtin_shufflevector(l0, l0, 4, 5, 6, 7);
            *(bf16x4*)&Bl[br][bc + 8]  = __builtin_shufflevector(l1, l1, 0, 1, 2, 3);
            *(bf16x4*)&Bl[br][bc + 12] = __builtin_shufflevector(l1, l1, 4, 5, 6, 7);
        }
        __syncthreads();

        // ---- compute ----
        int mrow = wave * 16 + r;
        bf16x4 a0 = *(bf16x4*)&Ah[mrow][g * 4];
        bf16x4 a1 = *(bf16x4*)&Ah[mrow][16 + g * 4];
        bf16x8 a_h = __builtin_shufflevector(a0, a1, 0, 1, 2, 3, 4, 5, 6, 7);
        bf16x8 a_l;
        if (split) {
            bf16x4 c0 = *(bf16x4*)&Al[mrow][g * 4];
            bf16x4 c1 = *(bf16x4*)&Al[mrow][16 + g * 4];
            a_l = __builtin_shufflevector(c0, c1, 0, 1, 2, 3, 4, 5, 6, 7);
        }
#pragma unroll
        for (int nt = 0; nt < 8; ++nt) {
            int nr = nt * 16 + r;
            bf16x4 b0 = *(bf16x4*)&Bh[nr][g * 4];
            bf16x4 b1 = *(bf16x4*)&Bh[nr][16 + g * 4];
            bf16x8 b_h = __builtin_shufflevector(b0, b1, 0, 1, 2, 3, 4, 5, 6, 7);
            bf16x4 d0 = *(bf16x4*)&Bl[nr][g * 4];
            bf16x4 d1 = *(bf16x4*)&Bl[nr][16 + g * 4];
            bf16x8 b_l = __builtin_shufflevector(d0, d1, 0, 1, 2, 3, 4, 5, 6, 7);
            acc[nt] = __builtin_amdgcn_mfma_f32_16x16x32_bf16(a_h, b_h, acc[nt], 0, 0, 0);
            acc[nt] = __builtin_amdgcn_mfma_f32_16x16x32_bf16(a_h, b_l, acc[nt], 0, 0, 0);
            if (split)
                acc[nt] = __builtin_amdgcn_mfma_f32_16x16x32_bf16(a_l, b_h, acc[nt], 0, 0, 0);
        }
        __syncthreads();
    }

    // ---- epilogue: C[row=(g*4+q)][col=r] per tile ----
#pragma unroll
    for (int nt = 0; nt < 8; ++nt) {
        int col = nt * 16 + r;
        float bv = bias[col];
#pragma unroll
        for (int q = 0; q < 4; ++q) {
            int row = row0 + wave * 16 + g * 4 + q;
            if (row < N_NODES) {
                float v = fmaxf(acc[nt][q] + bv, 0.f);
                C[(size_t)row * DIM + col] = v;
                if (Cb) Cb[(size_t)row * DIM + col] = (bf16)v;
            }
        }
    }
}

// ---------------- launch ----------------

extern "C" void kernel_launch(void* const* d_in, const int* in_sizes, int n_in,
                              void* d_out, int out_size, void* d_ws, size_t ws_size,
                              hipStream_t stream) {
    const float* x   = (const float*)d_in[0];
    const int*   ei  = (const int*)d_in[1];
    const float* W1l = (const float*)d_in[2];
    const float* b1  = (const float*)d_in[3];
    const float* W1r = (const float*)d_in[4];
    const float* W2l = (const float*)d_in[5];
    const float* b2  = (const float*)d_in[6];
    const float* W2r = (const float*)d_in[7];
    float* out = (float*)d_out;

    const int* src = ei;
    const int* dst = ei + N_EDGES;

    char* ws = (char*)d_ws;
    int*  deg    = (int*)(ws + 0);              // 200,000 B
    int*  fill   = (int*)(ws + 200064);         // 200,000 B
    int*  rowptr = (int*)(ws + 400128);         // 200,004 B
    int*  srt    = (int*)(ws + 600192);         // 3,200,000 B
    bf16* xbf    = (bf16*)(ws + 3800320);       // 12.8 MB (x bf16; later reused as h bf16)
    bf16* aggbf  = (bf16*)(ws + 16600320);      // 12.8 MB
    bf16* Wh1    = (bf16*)(ws + 29400320);      // 64 KB each
    bf16* Wl1    = Wh1 + 32768;
    bf16* Wh2    = Wh1 + 65536;
    bf16* Wl2    = Wh1 + 98304;                 // ends at ~29.66 MB

    hipMemsetAsync(ws, 0, 400128, stream);

    dim3 blk(256);
    k_count<<<dim3((N_EDGES + 255) / 256), blk, 0, stream>>>(dst, deg);
    k_scan<<<dim3(1), dim3(1024), 0, stream>>>(deg, rowptr);
    k_scatter<<<dim3((N_EDGES + 255) / 256), blk, 0, stream>>>(src, dst, rowptr, fill, srt);

    k_xtobf<<<dim3((N_NODES * DIM / 4 + 255) / 256), blk, 0, stream>>>(x, xbf);
    k_splitW<<<dim3(256), blk, 0, stream>>>(W1l, W1r, W2l, W2r, Wh1, Wl1, Wh2, Wl2);

    dim3 grdA((N_NODES * 64 + 255) / 256);
    dim3 grdG((N_NODES + 63) / 64);

    // layer 1: h (-> d_out f32, xbf bf16) = relu(agg1 @ W1l^T + b1 + x @ W1r^T)
    k_aggregate<<<grdA, blk, 0, stream>>>(xbf, rowptr, srt, aggbf);
    k_gemm<<<grdG, blk, 0, stream>>>(aggbf, x, Wh1, Wl1, b1, out, xbf);

    // layer 2: out = relu(agg2 @ W2l^T + b2 + h @ W2r^T)
    k_aggregate<<<grdA, blk, 0, stream>>>(xbf, rowptr, srt, aggbf);
    k_gemm<<<grdG, blk, 0, stream>>>(aggbf, out, Wh2, Wl2, b2, out, (bf16*)nullptr);
}

// Round 3
// 268.402 us; speedup vs baseline: 1.6871x; 1.3846x over previous
//
#include <hip/hip_runtime.h>

#define N_NODES 50000
#define N_EDGES 800000
#define DIM 128
#define NCHUNK 3125   // N_NODES / 16

typedef _Float16 f16;
typedef _Float16 f16x4 __attribute__((ext_vector_type(4)));
typedef _Float16 f16x8 __attribute__((ext_vector_type(8)));
typedef float    f32x4 __attribute__((ext_vector_type(4)));

// ---------------- CSR build ----------------

__global__ __launch_bounds__(256) void k_count(const int* __restrict__ dst, int* __restrict__ deg) {
    int e = blockIdx.x * 256 + threadIdx.x;
    if (e < N_EDGES) atomicAdd(&deg[dst[e]], 1);
}

__global__ __launch_bounds__(1024) void k_scan(const int* __restrict__ deg, int* __restrict__ rowptr) {
    __shared__ int sm[1024];
    int t = threadIdx.x;
    const int chunk = (N_NODES + 1023) >> 10;
    int beg = t * chunk;
    int end = beg + chunk;
    if (beg > N_NODES) beg = N_NODES;
    if (end > N_NODES) end = N_NODES;
    int sum = 0;
    for (int i = beg; i < end; ++i) sum += deg[i];
    sm[t] = sum;
    __syncthreads();
    for (int off = 1; off < 1024; off <<= 1) {
        int v = (t >= off) ? sm[t - off] : 0;
        __syncthreads();
        sm[t] += v;
        __syncthreads();
    }
    int run = sm[t] - sum;
    for (int i = beg; i < end; ++i) { rowptr[i] = run; run += deg[i]; }
    if (t == 0) rowptr[N_NODES] = N_EDGES;
}

__global__ __launch_bounds__(256) void k_scatter(const int* __restrict__ src, const int* __restrict__ dst,
                                                 const int* __restrict__ rowptr, int* __restrict__ fill,
                                                 int* __restrict__ srt) {
    int e = blockIdx.x * 256 + threadIdx.x;
    if (e < N_EDGES) {
        int d = dst[e];
        int p = atomicAdd(&fill[d], 1);
        srt[rowptr[d] + p] = src[e];
    }
}

// ---------------- f32 -> f16 convert ----------------

__global__ __launch_bounds__(256) void k_xtof16(const float* __restrict__ x, f16* __restrict__ xh) {
    int i = blockIdx.x * 256 + threadIdx.x;
    if (i < (N_NODES * DIM) / 4) {
        float4 v = *(const float4*)(x + (size_t)i * 4);
        f16x4 o;
        o[0] = (f16)v.x; o[1] = (f16)v.y; o[2] = (f16)v.z; o[3] = (f16)v.w;
        *(f16x4*)(xh + (size_t)i * 4) = o;
    }
}

// ---------------- W -> MFMA fragment order (f16), Wcat[n][k] = k<128 ? Wl : Wr ----------------
// frag element j of (nt,kk,lane): k = kk*32 + g*4 + (j&3) + 16*(j>=4), n = nt*16 + r

__global__ __launch_bounds__(256) void k_prepW(const float* __restrict__ W1l, const float* __restrict__ W1r,
                                               const float* __restrict__ W2l, const float* __restrict__ W2r,
                                               f16* __restrict__ Wf1, f16* __restrict__ Wf2) {
    int t = blockIdx.x * 256 + threadIdx.x;
    if (t >= 8192) return;
    int layer = t >> 12;
    int nt = (t >> 9) & 7;
    int kk = (t >> 6) & 7;
    int lane = t & 63;
    int r = lane & 15, g = lane >> 4;
    int n = nt * 16 + r;
    const float* Wl_ = layer ? W2l : W1l;
    const float* Wr_ = layer ? W2r : W1r;
    f16x8 frag;
#pragma unroll
    for (int j = 0; j < 8; ++j) {
        int k = kk * 32 + g * 4 + (j & 3) + ((j >> 2) << 4);
        float f = (k < 128) ? Wl_[n * 128 + k] : Wr_[n * 128 + (k - 128)];
        frag[j] = (f16)f;
    }
    f16* dst = (layer ? Wf2 : Wf1) + ((size_t)((nt * 8 + kk) * 64 + lane)) * 8;
    *(f16x8*)dst = frag;
}

// ---------------- mean aggregation: one wave per node, half-wave per row, unroll 2 ----------------

__device__ inline f32x4 cvt4(f16x4 v) { return __builtin_convertvector(v, f32x4); }

__global__ __launch_bounds__(256) void k_aggregate(const f16* __restrict__ X, const int* __restrict__ rowptr,
                                                   const int* __restrict__ srt, f16* __restrict__ out) {
    int w = (blockIdx.x * 256 + threadIdx.x) >> 6;
    if (w >= N_NODES) return;
    int lane = threadIdx.x & 63;
    int half = lane >> 5;              // this half-wave handles edges beg+half, beg+half+2, ...
    int col = (lane & 31) * 4;         // 4 f16 columns per lane
    const f16* __restrict__ base = X + col;
    int beg = rowptr[w], end = rowptr[w + 1];
    f32x4 a0 = {0.f, 0.f, 0.f, 0.f}, a1 = {0.f, 0.f, 0.f, 0.f};
    int e = beg + half;
    while (e + 2 < end) {              // 2 rows per half per iter -> 4 rows in flight per wave
        int s0 = srt[e], s1 = srt[e + 2];
        f16x4 v0 = *(const f16x4*)(base + (size_t)s0 * DIM);
        f16x4 v1 = *(const f16x4*)(base + (size_t)s1 * DIM);
        a0 += cvt4(v0);
        a1 += cvt4(v1);
        e += 4;
    }
    if (e < end) {
        int s0 = srt[e];
        a0 += cvt4(*(const f16x4*)(base + (size_t)s0 * DIM));
    }
    a0 += a1;
#pragma unroll
    for (int j = 0; j < 4; ++j) a0[j] += __shfl_xor((float)a0[j], 32);
    if (half == 0) {
        float inv = 1.0f / fmaxf((float)(end - beg), 1.0f);
        f16x4 r;
#pragma unroll
        for (int j = 0; j < 4; ++j) r[j] = (f16)(a0[j] * inv);
        *(f16x4*)(out + (size_t)w * DIM + col) = r;
    }
}

// ---------------- MFMA dual GEMM: C = relu([agg|self] @ Wcat^T + b) ----------------
// Block: 512 thr = 8 waves. Stage Wf (64 KB frag-order) into LDS once; each wave
// owns one 16-row chunk; A fragments read direct from global; no syncs in compute.

__global__ __launch_bounds__(512) void k_gemm(const f16* __restrict__ Agg, const float* __restrict__ A2,
                                              const f16* __restrict__ Wf, const float* __restrict__ bias,
                                              float* __restrict__ C, f16* __restrict__ Cb) {
    __shared__ uint4 Bsm[4096];   // 64 KB: [nt][kk][lane] 16B fragments
    int t = threadIdx.x;
    const uint4* wsrc = (const uint4*)Wf;
#pragma unroll
    for (int i = 0; i < 8; ++i) Bsm[t + i * 512] = wsrc[t + i * 512];
    __syncthreads();

    int wave = t >> 6, lane = t & 63;
    int chunk = blockIdx.x * 8 + wave;
    if (chunk >= NCHUNK) return;
    int r = lane & 15, g = lane >> 4;
    size_t row = (size_t)chunk * 16 + r;

    f32x4 acc[8];
#pragma unroll
    for (int nt = 0; nt < 8; ++nt) acc[nt] = (f32x4){0.f, 0.f, 0.f, 0.f};

    // ---- agg half: kk 0..3, A already f16 ----
    const f16* arow = Agg + row * DIM;
#pragma unroll
    for (int kk = 0; kk < 4; ++kk) {
        f16x4 q0 = *(const f16x4*)(arow + kk * 32 + g * 4);
        f16x4 q1 = *(const f16x4*)(arow + kk * 32 + g * 4 + 16);
        f16x8 a = __builtin_shufflevector(q0, q1, 0, 1, 2, 3, 4, 5, 6, 7);
#pragma unroll
        for (int nt = 0; nt < 8; ++nt) {
            f16x8 b = *(const f16x8*)&Bsm[(nt * 8 + kk) * 64 + lane];
            acc[nt] = __builtin_amdgcn_mfma_f32_16x16x32_f16(a, b, acc[nt], 0, 0, 0);
        }
    }
    // ---- self half: kk 4..7, A f32 split into f16 hi+lo ----
    const float* xrow = A2 + row * DIM;
#pragma unroll
    for (int kk = 4; kk < 8; ++kk) {
        int kl = (kk - 4) * 32 + g * 4;
        float4 v0 = *(const float4*)(xrow + kl);
        float4 v1 = *(const float4*)(xrow + kl + 16);
        float f[8] = {v0.x, v0.y, v0.z, v0.w, v1.x, v1.y, v1.z, v1.w};
        f16x8 ah, al;
#pragma unroll
        for (int j = 0; j < 8; ++j) {
            f16 h = (f16)f[j];
            ah[j] = h;
            al[j] = (f16)(f[j] - (float)h);
        }
#pragma unroll
        for (int nt = 0; nt < 8; ++nt) {
            f16x8 b = *(const f16x8*)&Bsm[(nt * 8 + kk) * 64 + lane];
            acc[nt] = __builtin_amdgcn_mfma_f32_16x16x32_f16(ah, b, acc[nt], 0, 0, 0);
            acc[nt] = __builtin_amdgcn_mfma_f32_16x16x32_f16(al, b, acc[nt], 0, 0, 0);
        }
    }
    // ---- epilogue: C[row = chunk*16 + g*4 + q][col = nt*16 + r] ----
    size_t rbase = (size_t)chunk * 16 + g * 4;
#pragma unroll
    for (int nt = 0; nt < 8; ++nt) {
        int colc = nt * 16 + r;
        float bv = bias[colc];
#pragma unroll
        for (int q = 0; q < 4; ++q) {
            float v = fmaxf(acc[nt][q] + bv, 0.f);
            size_t idx = (rbase + q) * DIM + colc;
            C[idx] = v;
            if (Cb) Cb[idx] = (f16)v;
        }
    }
}

// ---------------- launch ----------------

extern "C" void kernel_launch(void* const* d_in, const int* in_sizes, int n_in,
                              void* d_out, int out_size, void* d_ws, size_t ws_size,
                              hipStream_t stream) {
    const float* x   = (const float*)d_in[0];
    const int*   ei  = (const int*)d_in[1];
    const float* W1l = (const float*)d_in[2];
    const float* b1  = (const float*)d_in[3];
    const float* W1r = (const float*)d_in[4];
    const float* W2l = (const float*)d_in[5];
    const float* b2  = (const float*)d_in[6];
    const float* W2r = (const float*)d_in[7];
    float* out = (float*)d_out;

    const int* src = ei;
    const int* dst = ei + N_EDGES;

    char* ws = (char*)d_ws;
    int*  deg    = (int*)(ws + 0);              // 200,000 B
    int*  fill   = (int*)(ws + 200064);         // 200,000 B
    int*  rowptr = (int*)(ws + 400128);         // 200,004 B
    int*  srt    = (int*)(ws + 600192);         // 3,200,000 B
    f16*  xh     = (f16*)(ws + 3800320);        // 12.8 MB (x f16, later h f16)
    f16*  aggh   = (f16*)(ws + 16600320);       // 12.8 MB
    f16*  Wf1    = (f16*)(ws + 29400320);       // 64 KB frag-order
    f16*  Wf2    = Wf1 + 32768;                 // 64 KB

    hipMemsetAsync(ws, 0, 400128, stream);

    dim3 blk(256);
    k_count<<<dim3((N_EDGES + 255) / 256), blk, 0, stream>>>(dst, deg);
    k_scan<<<dim3(1), dim3(1024), 0, stream>>>(deg, rowptr);
    k_scatter<<<dim3((N_EDGES + 255) / 256), blk, 0, stream>>>(src, dst, rowptr, fill, srt);

    k_xtof16<<<dim3((N_NODES * DIM / 4 + 255) / 256), blk, 0, stream>>>(x, xh);
    k_prepW<<<dim3(32), blk, 0, stream>>>(W1l, W1r, W2l, W2r, Wf1, Wf2);

    dim3 grdA((N_NODES * 64 + 255) / 256);
    dim3 grdG((NCHUNK + 7) / 8);

    // layer 1: h (f32 -> d_out, f16 -> xh) = relu(agg1 @ W1l^T + b1 + x @ W1r^T)
    k_aggregate<<<grdA, blk, 0, stream>>>(xh, rowptr, srt, aggh);
    k_gemm<<<grdG, dim3(512), 0, stream>>>(aggh, x, Wf1, b1, out, xh);

    // layer 2: out = relu(agg2 @ W2l^T + b2 + h @ W2r^T)   (in-place self-read safe per-wave)
    k_aggregate<<<grdA, blk, 0, stream>>>(xh, rowptr, srt, aggh);
    k_gemm<<<grdG, dim3(512), 0, stream>>>(aggh, out, Wf2, b2, out, (f16*)nullptr);
}

// Round 4
// 189.016 us; speedup vs baseline: 2.3957x; 1.4200x over previous
//
#include <hip/hip_runtime.h>

#define N_NODES 50000
#define N_EDGES 800000
#define DIM 128
#define NCHUNK 3125     // N_NODES / 16
#define SCAN_B 49       // ceil(50000 / 1024)

typedef _Float16 f16;
typedef _Float16 f16x4 __attribute__((ext_vector_type(4)));
typedef _Float16 f16x8 __attribute__((ext_vector_type(8)));
typedef float    f32x4 __attribute__((ext_vector_type(4)));
typedef float    f32x8 __attribute__((ext_vector_type(8)));

// ---------------- CSR build ----------------

__global__ __launch_bounds__(256) void k_count(const int* __restrict__ dst, int* __restrict__ deg) {
    int e = blockIdx.x * 256 + threadIdx.x;
    if (e < N_EDGES) atomicAdd(&deg[dst[e]], 1);
}

// Phase A: block-local scan (1024 elems/block), exclusive into rowptr, block sum out
__global__ __launch_bounds__(1024) void k_scanA(const int* __restrict__ deg, int* __restrict__ rowptr,
                                                int* __restrict__ bsum) {
    __shared__ int sm[1024];
    int t = threadIdx.x;
    int i = blockIdx.x * 1024 + t;
    int v = (i < N_NODES) ? deg[i] : 0;
    int orig = v;
    sm[t] = v;
    __syncthreads();
    for (int off = 1; off < 1024; off <<= 1) {
        int u = (t >= off) ? sm[t - off] : 0;
        __syncthreads();
        sm[t] += u;
        __syncthreads();
    }
    if (i < N_NODES) rowptr[i] = sm[t] - orig;          // exclusive within block
    if (t == 1023) bsum[blockIdx.x] = sm[t];            // block total
}

// Phase B: one wave scans the SCAN_B block sums -> exclusive block offsets
__global__ __launch_bounds__(64) void k_scanB(const int* __restrict__ bsum, int* __restrict__ boff,
                                              int* __restrict__ rowptr) {
    int t = threadIdx.x;
    int orig = (t < SCAN_B) ? bsum[t] : 0;
    int v = orig;
    for (int off = 1; off < 64; off <<= 1) {
        int u = __shfl_up(v, off);
        if (t >= off) v += u;
    }
    if (t < SCAN_B) boff[t] = v - orig;                 // exclusive
    if (t == 63) rowptr[N_NODES] = N_EDGES;
}

// Phase C: add block offsets
__global__ __launch_bounds__(1024) void k_scanC(int* __restrict__ rowptr, const int* __restrict__ boff) {
    int i = blockIdx.x * 1024 + threadIdx.x;
    if (i < N_NODES) rowptr[i] += boff[blockIdx.x];
}

__global__ __launch_bounds__(256) void k_scatter(const int* __restrict__ src, const int* __restrict__ dst,
                                                 const int* __restrict__ rowptr, int* __restrict__ fill,
                                                 int* __restrict__ srt) {
    int e = blockIdx.x * 256 + threadIdx.x;
    if (e < N_EDGES) {
        int d = dst[e];
        int p = atomicAdd(&fill[d], 1);
        srt[rowptr[d] + p] = src[e];
    }
}

// ---------------- f32 -> f16 convert ----------------

__global__ __launch_bounds__(256) void k_xtof16(const float* __restrict__ x, f16* __restrict__ xh) {
    int i = blockIdx.x * 256 + threadIdx.x;
    if (i < (N_NODES * DIM) / 4) {
        float4 v = *(const float4*)(x + (size_t)i * 4);
        f16x4 o;
        o[0] = (f16)v.x; o[1] = (f16)v.y; o[2] = (f16)v.z; o[3] = (f16)v.w;
        *(f16x4*)(xh + (size_t)i * 4) = o;
    }
}

// ---------------- W -> MFMA fragment order (f16), Wcat[n][k] = k<128 ? Wl : Wr ----------------

__global__ __launch_bounds__(256) void k_prepW(const float* __restrict__ W1l, const float* __restrict__ W1r,
                                               const float* __restrict__ W2l, const float* __restrict__ W2r,
                                               f16* __restrict__ Wf1, f16* __restrict__ Wf2) {
    int t = blockIdx.x * 256 + threadIdx.x;
    if (t >= 8192) return;
    int layer = t >> 12;
    int nt = (t >> 9) & 7;
    int kk = (t >> 6) & 7;
    int lane = t & 63;
    int r = lane & 15, g = lane >> 4;
    int n = nt * 16 + r;
    const float* Wl_ = layer ? W2l : W1l;
    const float* Wr_ = layer ? W2r : W1r;
    f16x8 frag;
#pragma unroll
    for (int j = 0; j < 8; ++j) {
        int k = kk * 32 + g * 4 + (j & 3) + ((j >> 2) << 4);
        float f = (k < 128) ? Wl_[n * 128 + k] : Wr_[n * 128 + (k - 128)];
        frag[j] = (f16)f;
    }
    f16* dst = (layer ? Wf2 : Wf1) + ((size_t)((nt * 8 + kk) * 64 + lane)) * 8;
    *(f16x8*)dst = frag;
}

// ---------------- mean aggregation: one wave/node, 16 lanes/row (f16x8), quarter-wave streams ----------------

__global__ __launch_bounds__(256) void k_aggregate(const f16* __restrict__ X, const int* __restrict__ rowptr,
                                                   const int* __restrict__ srt, f16* __restrict__ out) {
    int w = (blockIdx.x * 256 + threadIdx.x) >> 6;
    if (w >= N_NODES) return;
    int lane = threadIdx.x & 63;
    int q = lane >> 4;                 // quarter-wave 0..3: handles edges beg+q, beg+q+4, ...
    int col = (lane & 15) * 8;         // 8 f16 columns per lane
    const f16* __restrict__ base = X + col;
    int beg = rowptr[w], end = rowptr[w + 1];
    f32x8 A0 = {0.f,0.f,0.f,0.f,0.f,0.f,0.f,0.f};
    f32x8 A1 = {0.f,0.f,0.f,0.f,0.f,0.f,0.f,0.f};
    int e = beg + q;
    while (e + 4 < end) {              // 2 rows/quarter in flight -> 8 per wave
        int s0 = srt[e], s1 = srt[e + 4];
        f16x8 v0 = *(const f16x8*)(base + (size_t)s0 * DIM);
        f16x8 v1 = *(const f16x8*)(base + (size_t)s1 * DIM);
        A0 += __builtin_convertvector(v0, f32x8);
        A1 += __builtin_convertvector(v1, f32x8);
        e += 8;
    }
    if (e < end) {
        int s0 = srt[e];
        A0 += __builtin_convertvector(*(const f16x8*)(base + (size_t)s0 * DIM), f32x8);
    }
    A0 += A1;
#pragma unroll
    for (int j = 0; j < 8; ++j) {
        float s = A0[j];
        s += __shfl_xor(s, 16);
        s += __shfl_xor(s, 32);
        A0[j] = s;
    }
    if (lane < 16) {
        float inv = 1.0f / fmaxf((float)(end - beg), 1.0f);
        f16x8 r;
#pragma unroll
        for (int j = 0; j < 8; ++j) r[j] = (f16)(A0[j] * inv);
        *(f16x8*)(out + (size_t)w * DIM + col) = r;
    }
}

// ---------------- MFMA dual GEMM: C = relu([agg|self] @ Wcat^T + b) ----------------

__global__ __launch_bounds__(512) void k_gemm(const f16* __restrict__ Agg, const float* __restrict__ A2,
                                              const f16* __restrict__ Wf, const float* __restrict__ bias,
                                              float* __restrict__ C, f16* __restrict__ Cb) {
    __shared__ uint4 Bsm[4096];   // 64 KB: [nt][kk][lane] 16B fragments
    int t = threadIdx.x;
    const uint4* wsrc = (const uint4*)Wf;
#pragma unroll
    for (int i = 0; i < 8; ++i) Bsm[t + i * 512] = wsrc[t + i * 512];
    __syncthreads();

    int wave = t >> 6, lane = t & 63;
    int chunk = blockIdx.x * 8 + wave;
    if (chunk >= NCHUNK) return;
    int r = lane & 15, g = lane >> 4;
    size_t row = (size_t)chunk * 16 + r;

    f32x4 acc[8];
#pragma unroll
    for (int nt = 0; nt < 8; ++nt) acc[nt] = (f32x4){0.f, 0.f, 0.f, 0.f};

    const f16* arow = Agg + row * DIM;
#pragma unroll
    for (int kk = 0; kk < 4; ++kk) {
        f16x4 q0 = *(const f16x4*)(arow + kk * 32 + g * 4);
        f16x4 q1 = *(const f16x4*)(arow + kk * 32 + g * 4 + 16);
        f16x8 a = __builtin_shufflevector(q0, q1, 0, 1, 2, 3, 4, 5, 6, 7);
#pragma unroll
        for (int nt = 0; nt < 8; ++nt) {
            f16x8 b = *(const f16x8*)&Bsm[(nt * 8 + kk) * 64 + lane];
            acc[nt] = __builtin_amdgcn_mfma_f32_16x16x32_f16(a, b, acc[nt], 0, 0, 0);
        }
    }
    const float* xrow = A2 + row * DIM;
#pragma unroll
    for (int kk = 4; kk < 8; ++kk) {
        int kl = (kk - 4) * 32 + g * 4;
        float4 v0 = *(const float4*)(xrow + kl);
        float4 v1 = *(const float4*)(xrow + kl + 16);
        float f[8] = {v0.x, v0.y, v0.z, v0.w, v1.x, v1.y, v1.z, v1.w};
        f16x8 ah, al;
#pragma unroll
        for (int j = 0; j < 8; ++j) {
            f16 h = (f16)f[j];
            ah[j] = h;
            al[j] = (f16)(f[j] - (float)h);
        }
#pragma unroll
        for (int nt = 0; nt < 8; ++nt) {
            f16x8 b = *(const f16x8*)&Bsm[(nt * 8 + kk) * 64 + lane];
            acc[nt] = __builtin_amdgcn_mfma_f32_16x16x32_f16(ah, b, acc[nt], 0, 0, 0);
            acc[nt] = __builtin_amdgcn_mfma_f32_16x16x32_f16(al, b, acc[nt], 0, 0, 0);
        }
    }
    size_t rbase = (size_t)chunk * 16 + g * 4;
#pragma unroll
    for (int nt = 0; nt < 8; ++nt) {
        int colc = nt * 16 + r;
        float bv = bias[colc];
#pragma unroll
        for (int q = 0; q < 4; ++q) {
            float v = fmaxf(acc[nt][q] + bv, 0.f);
            size_t idx = (rbase + q) * DIM + colc;
            C[idx] = v;
            if (Cb) Cb[idx] = (f16)v;
        }
    }
}

// ---------------- launch ----------------

extern "C" void kernel_launch(void* const* d_in, const int* in_sizes, int n_in,
                              void* d_out, int out_size, void* d_ws, size_t ws_size,
                              hipStream_t stream) {
    const float* x   = (const float*)d_in[0];
    const int*   ei  = (const int*)d_in[1];
    const float* W1l = (const float*)d_in[2];
    const float* b1  = (const float*)d_in[3];
    const float* W1r = (const float*)d_in[4];
    const float* W2l = (const float*)d_in[5];
    const float* b2  = (const float*)d_in[6];
    const float* W2r = (const float*)d_in[7];
    float* out = (float*)d_out;

    const int* src = ei;
    const int* dst = ei + N_EDGES;

    char* ws = (char*)d_ws;
    int*  deg    = (int*)(ws + 0);              // 200,000 B
    int*  fill   = (int*)(ws + 200064);         // 200,000 B
    int*  rowptr = (int*)(ws + 400128);         // 200,004 B
    int*  srt    = (int*)(ws + 600192);         // 3,200,000 B
    f16*  xh     = (f16*)(ws + 3800320);        // 12.8 MB (x f16, later h f16)
    f16*  aggh   = (f16*)(ws + 16600320);       // 12.8 MB
    f16*  Wf1    = (f16*)(ws + 29400320);       // 64 KB frag-order
    f16*  Wf2    = Wf1 + 32768;                 // 64 KB
    int*  bsum   = (int*)(ws + 29531392);       // 196 B
    int*  boff   = (int*)(ws + 29531648);       // 196 B

    hipMemsetAsync(ws, 0, 400128, stream);      // deg + fill

    dim3 blk(256);
    k_count<<<dim3((N_EDGES + 255) / 256), blk, 0, stream>>>(dst, deg);
    k_scanA<<<dim3(SCAN_B), dim3(1024), 0, stream>>>(deg, rowptr, bsum);
    k_scanB<<<dim3(1), dim3(64), 0, stream>>>(bsum, boff, rowptr);
    k_scanC<<<dim3(SCAN_B), dim3(1024), 0, stream>>>(rowptr, boff);
    k_scatter<<<dim3((N_EDGES + 255) / 256), blk, 0, stream>>>(src, dst, rowptr, fill, srt);

    k_xtof16<<<dim3((N_NODES * DIM / 4 + 255) / 256), blk, 0, stream>>>(x, xh);
    k_prepW<<<dim3(32), blk, 0, stream>>>(W1l, W1r, W2l, W2r, Wf1, Wf2);

    dim3 grdA((N_NODES * 64 + 255) / 256);
    dim3 grdG((NCHUNK + 7) / 8);

    // layer 1: h (f32 -> d_out, f16 -> xh) = relu(agg1 @ W1l^T + b1 + x @ W1r^T)
    k_aggregate<<<grdA, blk, 0, stream>>>(xh, rowptr, srt, aggh);
    k_gemm<<<grdG, dim3(512), 0, stream>>>(aggh, x, Wf1, b1, out, xh);

    // layer 2: out = relu(agg2 @ W2l^T + b2 + h @ W2r^T)
    k_aggregate<<<grdA, blk, 0, stream>>>(xh, rowptr, srt, aggh);
    k_gemm<<<grdG, dim3(512), 0, stream>>>(aggh, out, Wf2, b2, out, (f16*)nullptr);
}